// Round 2
// baseline (352.888 us; speedup 1.0000x reference)
//
#include <hip/hip_runtime.h>

#define N_NODES 50000
#define N_EDGES 800000
#define D 128
#define CAP 64      // bucket capacity per dst node (max in-degree ~45 for this dataset)
#define OVF_CAP 4096
#define GN 64       // nodes per GEMM block
#define NSLICE 8    // feature-dim slices (16 cols each)
#define SLICE_U4 ((size_t)N_NODES * 4)  // ushort4 (bf16) or float4 (msg) elements per slice

#define NPART 8        // dst/src partitions == #XCDs
#define PART_SZ 6250   // 50000 / 8
#define NCHUNK 128     // edge chunks per partition scan (chunk = 6250 edges)
#define HS_BLOCKS 1024 // scatter grid; blocks self-assign to their XCD's partition

typedef unsigned short bf16_t;

__device__ inline float bf2f(bf16_t u) {
    union { unsigned int i; float f; } v;
    v.i = ((unsigned int)u) << 16;
    return v.f;
}
__device__ inline bf16_t f2bf(float f) {
    union { float f; unsigned int i; } v;
    v.f = f;
    unsigned int u = v.i;
    unsigned int r = (u + 0x7FFFu + ((u >> 16) & 1u)) >> 16;  // RNE
    return (bf16_t)r;
}

// ---------------- XCD-partitioned histogram + bucket-CSR scatter ----------------
// Round-2 fixes vs round-1 (WRITE_SIZE was 54 MB for 6.4 MB of bucket = line thrash):
//  (a) partition = ACTUAL XCD id (s_getreg HW_REG_XCC_ID), not blockIdx%8 — locality
//      by construction; per-partition atomic tickets load-balance the edge chunks
//      across however many blocks land on each XCD.
//  (b) edge reads are non-temporal (`nt`): the 6.4 MB/pass edge stream no longer
//      allocates in L2, so it cannot evict the dirty bucket lines (~800 KB/XCD).
//      Bucket lines accumulate all their writes and write back once.
__global__ void hist_scatter_part(const int* __restrict__ src, const int* __restrict__ dst,
                                  int* __restrict__ cnt_s, int* __restrict__ cnt_d,
                                  unsigned short* __restrict__ bucket,
                                  int* __restrict__ ovf_cnt, int2* __restrict__ ovf,
                                  int* __restrict__ ticket, int nE) {
    __shared__ int s_j;
    int p;
    asm volatile("s_getreg_b32 %0, hwreg(HW_REG_XCC_ID)" : "=s"(p));
    p &= (NPART - 1);
    const int chunk = (nE + NCHUNK - 1) / NCHUNK;
    for (;;) {
        __syncthreads();
        if (threadIdx.x == 0) s_j = atomicAdd(&ticket[p], 1);
        __syncthreads();
        int j = s_j;
        if (j >= NCHUNK) return;
        int e0 = j * chunk;
        int e1 = min(e0 + chunk, nE);
        for (int e = e0 + (int)threadIdx.x; e < e1; e += 256) {
            int s = __builtin_nontemporal_load(src + e);
            int d = __builtin_nontemporal_load(dst + e);
            if (s / PART_SZ == p) atomicAdd(&cnt_s[s], 1);
            if (d / PART_SZ == p) {
                int q = atomicAdd(&cnt_d[d], 1);
                if (q < CAP) {
                    bucket[(size_t)d * CAP + q] = (unsigned short)s;
                } else {
                    int o = atomicAdd(ovf_cnt, 1);
                    if (o < OVF_CAP) ovf[o] = make_int2(d, s);
                }
            }
        }
    }
}

// ---------------- fused: rs arrays + xs = bf16(x * rs_out), slice-major ----------------
__global__ void prescale_kernel(const float4* __restrict__ x, const int* __restrict__ cnt_s,
                                const int* __restrict__ cnt_d,
                                float* __restrict__ rs_out, float* __restrict__ rs_in,
                                ushort4* __restrict__ xs4, int nN) {
    int node = blockIdx.x * 8 + (threadIdx.x >> 5);
    int c = threadIdx.x & 31;
    if (node >= nN) return;
    float rs_o = 0.0f;
    if (c == 0) {
        rs_o = rsqrtf(fmaxf((float)cnt_s[node], 1.0f));
        rs_out[node] = rs_o;
        rs_in[node] = rsqrtf(fmaxf((float)cnt_d[node], 1.0f));
    }
    rs_o = __shfl(rs_o, threadIdx.x & 32);  // broadcast from node's lane 0 / 32
    float4 v = x[(size_t)node * 32 + c];
    ushort4 o;
    o.x = f2bf(v.x * rs_o);
    o.y = f2bf(v.y * rs_o);
    o.z = f2bf(v.z * rs_o);
    o.w = f2bf(v.w * rs_o);
    xs4[(size_t)(c >> 2) * SLICE_U4 + (size_t)node * 4 + (c & 3)] = o;
}

// ---------------- sliced gather over bucket CSR: slice = blockIdx%8, 4 lanes/node ----------------
__global__ void gather_kernel(const ushort4* __restrict__ xs4, const int* __restrict__ cnt_d,
                              const unsigned short* __restrict__ bucket,
                              float4* __restrict__ msg4, int nN) {
    int s = blockIdx.x & (NSLICE - 1);
    int g = blockIdx.x >> 3;
    int node = g * 64 + (threadIdx.x >> 2);
    int lane = threadIdx.x & 3;
    if (node >= nN) return;
    const ushort4* base = xs4 + (size_t)s * SLICE_U4;
    const unsigned short* bk = bucket + (size_t)node * CAP;
    int cnt = min(cnt_d[node], CAP);
    float4 a0 = make_float4(0.f, 0.f, 0.f, 0.f);
    float4 a1 = make_float4(0.f, 0.f, 0.f, 0.f);
    int e = 0;
    for (; e + 1 < cnt; e += 2) {
        int s0 = bk[e];
        int s1 = bk[e + 1];
        ushort4 v0 = base[(size_t)s0 * 4 + lane];
        ushort4 v1 = base[(size_t)s1 * 4 + lane];
        a0.x += bf2f(v0.x); a0.y += bf2f(v0.y); a0.z += bf2f(v0.z); a0.w += bf2f(v0.w);
        a1.x += bf2f(v1.x); a1.y += bf2f(v1.y); a1.z += bf2f(v1.z); a1.w += bf2f(v1.w);
    }
    if (e < cnt) {
        int s0 = bk[e];
        ushort4 v0 = base[(size_t)s0 * 4 + lane];
        a0.x += bf2f(v0.x); a0.y += bf2f(v0.y); a0.z += bf2f(v0.z); a0.w += bf2f(v0.w);
    }
    a0.x += a1.x; a0.y += a1.y; a0.z += a1.z; a0.w += a1.w;
    msg4[(size_t)s * SLICE_U4 + (size_t)node * 4 + lane] = a0;
}

// ---------------- overflow fixup (no-op when ovf_cnt==0; exact replay otherwise) ----------------
__global__ void ovf_kernel(const int2* __restrict__ ovf, const int* __restrict__ ovf_cnt,
                           const ushort4* __restrict__ xs4, float* __restrict__ msg) {
    int n = min(*ovf_cnt, OVF_CAP);
    int lane = threadIdx.x & 31;            // 32 lanes = 128 cols
    for (int i = (int)(threadIdx.x >> 5); i < n; i += 8) {
        int2 ds = ovf[i];
        int sl = lane >> 2, sub = lane & 3;
        ushort4 v = xs4[(size_t)sl * SLICE_U4 + (size_t)ds.y * 4 + sub];
        float* m = msg + ((size_t)sl * SLICE_U4 + (size_t)ds.x * 4 + sub) * 4;
        atomicAdd(m + 0, bf2f(v.x));
        atomicAdd(m + 1, bf2f(v.y));
        atomicAdd(m + 2, bf2f(v.z));
        atomicAdd(m + 3, bf2f(v.w));
    }
}

// ---------------- weight shuffle: WTs[k4*128 + col] = {W[4k4+j][col]} ----------------
__global__ void wshuf_kernel(const float* __restrict__ W1, float4* __restrict__ WTs1,
                             const float* __restrict__ W2, float4* __restrict__ WTs2) {
    int col = threadIdx.x;   // 0..127
    int k4 = blockIdx.x;     // 0..31
    const float* W = blockIdx.y ? W2 : W1;
    float4* WTs = blockIdx.y ? WTs2 : WTs1;
    WTs[k4 * D + col] = make_float4(W[(4 * k4 + 0) * D + col], W[(4 * k4 + 1) * D + col],
                                    W[(4 * k4 + 2) * D + col], W[(4 * k4 + 3) * D + col]);
}

// ---------------- dense layer: 64 nodes x 128 cols per block, 8x4 per thread ----------------
template <bool RELU_OUTSCALE, bool OUT_SLICED>
__global__ void gemm_kernel(const float4* __restrict__ msg4, const float* __restrict__ rs_in,
                            const float* __restrict__ rs_out, const float4* __restrict__ WTs,
                            const float* __restrict__ bias, void* __restrict__ outp, int nN) {
    __shared__ float4 sA[GN * 32];  // [node][k4], 32 KB
    int tid = threadIdx.x;          // 0..255
    int n0 = blockIdx.x * GN;
#pragma unroll
    for (int it = 0; it < 8; it++) {
        int idx = it * 256 + tid;
        int node = n0 + (idx >> 5);
        int c = idx & 31;           // k4 index
        sA[idx] = (node < nN)
            ? msg4[(size_t)(c >> 2) * SLICE_U4 + (size_t)node * 4 + (c & 3)]
            : make_float4(0.f, 0.f, 0.f, 0.f);
    }
    __syncthreads();
    int tx = tid & 31;   // cols tx, tx+32, tx+64, tx+96
    int ty = tid >> 5;   // nodes ty + 8*i
    float acc[8][4];
#pragma unroll
    for (int i = 0; i < 8; i++)
#pragma unroll
        for (int j = 0; j < 4; j++) acc[i][j] = 0.0f;

    for (int k4 = 0; k4 < 32; k4++) {
        float4 w0 = WTs[k4 * D + tx];
        float4 w1 = WTs[k4 * D + tx + 32];
        float4 w2 = WTs[k4 * D + tx + 64];
        float4 w3 = WTs[k4 * D + tx + 96];
#pragma unroll
        for (int i = 0; i < 8; i++) {
            float4 a = sA[(ty + 8 * i) * 32 + k4];
            acc[i][0] += a.x * w0.x + a.y * w0.y + a.z * w0.z + a.w * w0.w;
            acc[i][1] += a.x * w1.x + a.y * w1.y + a.z * w1.z + a.w * w1.w;
            acc[i][2] += a.x * w2.x + a.y * w2.y + a.z * w2.z + a.w * w2.w;
            acc[i][3] += a.x * w3.x + a.y * w3.y + a.z * w3.z + a.w * w3.w;
        }
    }
    float b0 = bias[tx], b1 = bias[tx + 32], b2 = bias[tx + 64], b3 = bias[tx + 96];
#pragma unroll
    for (int i = 0; i < 8; i++) {
        int node = n0 + ty + 8 * i;
        if (node >= nN) continue;
        float ri = rs_in[node];
        float v[4];
        v[0] = acc[i][0] * ri + b0;
        v[1] = acc[i][1] * ri + b1;
        v[2] = acc[i][2] * ri + b2;
        v[3] = acc[i][3] * ri + b3;
        if (RELU_OUTSCALE) {
            float ro = rs_out[node];
#pragma unroll
            for (int j = 0; j < 4; j++) v[j] = fmaxf(v[j], 0.0f) * ro;
        }
        if (OUT_SLICED) {
            bf16_t* o = (bf16_t*)outp;
#pragma unroll
            for (int j = 0; j < 4; j++) {
                int col = tx + 32 * j;
                o[(size_t)(col >> 4) * ((size_t)N_NODES * 16) + (size_t)node * 16 + (col & 15)] =
                    f2bf(v[j]);
            }
        } else {
            float* o = (float*)outp + (size_t)node * D;
            o[tx] = v[0]; o[tx + 32] = v[1]; o[tx + 64] = v[2]; o[tx + 96] = v[3];
        }
    }
}

static inline size_t align16(size_t x) { return (x + 15) & ~(size_t)15; }

extern "C" void kernel_launch(void* const* d_in, const int* in_sizes, int n_in,
                              void* d_out, int out_size, void* d_ws, size_t ws_size,
                              hipStream_t stream) {
    const float* x   = (const float*)d_in[0];
    const int*   src = (const int*)d_in[1];
    const int*   dst = (const int*)d_in[2];
    const float* W1  = (const float*)d_in[3];
    const float* b1  = (const float*)d_in[4];
    const float* W2  = (const float*)d_in[5];
    const float* b2  = (const float*)d_in[6];
    float* out = (float*)d_out;

    // workspace layout. xs aliases hs (both sliced bf16).
    char* p = (char*)d_ws;
    float*          msg     = (float*)p;          p += align16((size_t)N_NODES * D * sizeof(float));
    int*            cnt_s   = (int*)p;            p += align16(N_NODES * sizeof(int));
    int*            cnt_d   = (int*)p;            p += align16(N_NODES * sizeof(int));
    int*            ovf_cnt = (int*)p;            p += align16(16 * sizeof(int));  // [0]=ovf, [8..15]=tickets
    int2*           ovf     = (int2*)p;           p += align16((size_t)OVF_CAP * sizeof(int2));
    unsigned short* bucket  = (unsigned short*)p; p += align16((size_t)N_NODES * CAP * sizeof(unsigned short));
    float*          rs_out  = (float*)p;          p += align16(N_NODES * sizeof(float));
    float*          rs_in   = (float*)p;          p += align16(N_NODES * sizeof(float));
    float*          WTs1    = (float*)p;          p += align16((size_t)D * D * sizeof(float));
    float*          WTs2    = (float*)p;          p += align16((size_t)D * D * sizeof(float));
    bf16_t*         xs      = (bf16_t*)p;         // sliced bf16, aliased with hs (12.8 MB)
    bf16_t*         hs      = xs;

    // zero counters (cnt_s, cnt_d, ovf_cnt+tickets adjacent)
    hipMemsetAsync(cnt_s, 0, (char*)(ovf_cnt + 16) - (char*)cnt_s, stream);

    // weight shuffle (both layers, one tiny launch)
    wshuf_kernel<<<dim3(32, 2), D, 0, stream>>>(W1, (float4*)WTs1, W2, (float4*)WTs2);

    // XCD-partitioned histogram + bucket scatter: each block serves its OWN XCD's
    // partition (HW_REG_XCC_ID) via per-partition chunk tickets; edge stream is
    // non-temporal so dirty bucket lines stay L2-resident.
    hist_scatter_part<<<HS_BLOCKS, 256, 0, stream>>>(src, dst, cnt_s, cnt_d, bucket,
                                                     ovf_cnt, ovf, ovf_cnt + 8, N_EDGES);

    // rs arrays + xs = bf16(x * rs_out), slice-major
    prescale_kernel<<<(N_NODES + 7) / 8, 256, 0, stream>>>((const float4*)x, cnt_s, cnt_d,
                                                           rs_out, rs_in, (ushort4*)xs, N_NODES);

    // sliced gathers: 8 slices x 782 node-groups
    int ggrid = NSLICE * ((N_NODES + 63) / 64);

    // layer 1 aggregation: msg = sum xs[s]
    gather_kernel<<<ggrid, 256, 0, stream>>>((const ushort4*)xs, cnt_d, bucket,
                                             (float4*)msg, N_NODES);
    ovf_kernel<<<1, 256, 0, stream>>>(ovf, ovf_cnt, (const ushort4*)xs, msg);

    // layer 1 dense: hs = bf16( relu(rs_in * (msg @ W1) + b1) * rs_out ), slice-major
    gemm_kernel<true, true><<<(N_NODES + GN - 1) / GN, 256, 0, stream>>>(
        (const float4*)msg, rs_in, rs_out, (const float4*)WTs1, b1, hs, N_NODES);

    // layer 2 aggregation: msg = sum hs[s]
    gather_kernel<<<ggrid, 256, 0, stream>>>((const ushort4*)hs, cnt_d, bucket,
                                             (float4*)msg, N_NODES);
    ovf_kernel<<<1, 256, 0, stream>>>(ovf, ovf_cnt, (const ushort4*)hs, msg);

    // layer 2 dense: out = rs_in * (msg @ W2) + b2  (fp32 row-major)
    gemm_kernel<false, false><<<(N_NODES + GN - 1) / GN, 256, 0, stream>>>(
        (const float4*)msg, rs_in, nullptr, (const float4*)WTs2, b2, out, N_NODES);
}

// Round 3
// 300.059 us; speedup vs baseline: 1.1761x; 1.1761x over previous
//
#include <hip/hip_runtime.h>

#define N_NODES 50000
#define N_EDGES 800000
#define D 128
#define CAP 64      // bucket capacity per dst node (max in-degree ~45 for this dataset)
#define OVF_CAP 4096
#define GN 64       // nodes per GEMM block
#define NSLICE 8    // feature-dim slices (16 cols each)
#define SLICE_U4 ((size_t)N_NODES * 4)  // ushort4 (bf16) or float4 (msg) elements per slice

#define HB 160                       // counting-sort blocks (chunks)
#define CHUNK ((N_EDGES + HB - 1) / HB)   // 5000 edges per chunk
#define NW (N_NODES / 4)             // packed byte-counter words = 12500

typedef unsigned short bf16_t;

__device__ inline float bf2f(bf16_t u) {
    union { unsigned int i; float f; } v;
    v.i = ((unsigned int)u) << 16;
    return v.f;
}
__device__ inline bf16_t f2bf(float f) {
    union { float f; unsigned int i; } v;
    v.f = f;
    unsigned int u = v.i;
    unsigned int r = (u + 0x7FFFu + ((u >> 16) & 1u)) >> 16;  // RNE
    return (bf16_t)r;
}

// =============== counting-sort scatter (zero global atomics) ===============
// Global device-scope atomics on gfx950 execute memory-side (~32 B fabric
// write each; measured: WRITE_SIZE pinned at ~51 MB for 1.6 M atomics across
// rounds 0-2 regardless of partitioning). So we eliminate them: per-block
// LDS histograms with packed byte counters (max degree ~45 < 255, so 4
// counters per u32; SWAR adds can't carry across fields), exclusive scan
// over blocks, then LDS-cursor placement.

// ---- K1: per-chunk src/dst histograms in LDS, flushed dense to global ----
__global__ __launch_bounds__(1024) void hist_kernel(const int* __restrict__ src,
                                                    const int* __restrict__ dst,
                                                    unsigned int* __restrict__ Hs,
                                                    unsigned int* __restrict__ Hd, int nE) {
    __shared__ unsigned int hs[NW];   // 50 KB
    __shared__ unsigned int hd[NW];   // 50 KB
    for (int i = threadIdx.x; i < NW; i += 1024) { hs[i] = 0u; hd[i] = 0u; }
    __syncthreads();
    int e0 = blockIdx.x * CHUNK;
    int e1 = min(e0 + CHUNK, nE);
    for (int e = e0 + (int)threadIdx.x; e < e1; e += 1024) {
        int s = src[e];
        int d = dst[e];
        atomicAdd(&hs[s >> 2], 1u << (8 * (s & 3)));
        atomicAdd(&hd[d >> 2], 1u << (8 * (d & 3)));
    }
    __syncthreads();
    unsigned int* Hsb = Hs + (size_t)blockIdx.x * NW;
    unsigned int* Hdb = Hd + (size_t)blockIdx.x * NW;
    for (int i = threadIdx.x; i < NW; i += 1024) { Hsb[i] = hs[i]; Hdb[i] = hd[i]; }
}

// ---- K2: exclusive scan across blocks (dst) + totals (src & dst) ----
// blockIdx.y == 0: dst -> OFF + cnt_d ; blockIdx.y == 1: src -> cnt_s
__global__ void scan_kernel(const unsigned int* __restrict__ Hs,
                            const unsigned int* __restrict__ Hd,
                            unsigned int* __restrict__ OFF,
                            int* __restrict__ cnt_s, int* __restrict__ cnt_d) {
    int w = blockIdx.x * 256 + (int)threadIdx.x;
    if (w >= NW) return;
    if (blockIdx.y == 0) {
        unsigned int run = 0;
        for (int b = 0; b < HB; b++) {
            unsigned int v = Hd[(size_t)b * NW + w];
            OFF[(size_t)b * NW + w] = run;   // exclusive prefix, packed bytes (<=45 per field)
            run += v;                         // SWAR add: fields < 256, no cross-field carry
        }
        int4 c;
        c.x = (int)(run & 0xFFu); c.y = (int)((run >> 8) & 0xFFu);
        c.z = (int)((run >> 16) & 0xFFu); c.w = (int)(run >> 24);
        ((int4*)cnt_d)[w] = c;
    } else {
        unsigned int run = 0;
        for (int b = 0; b < HB; b++) run += Hs[(size_t)b * NW + w];
        int4 c;
        c.x = (int)(run & 0xFFu); c.y = (int)((run >> 8) & 0xFFu);
        c.z = (int)((run >> 16) & 0xFFu); c.w = (int)(run >> 24);
        ((int4*)cnt_s)[w] = c;
    }
}

// ---- K3: placement via packed LDS cursors (one LDS atomic per edge) ----
__global__ __launch_bounds__(1024) void place_kernel(const int* __restrict__ src,
                                                     const int* __restrict__ dst,
                                                     const unsigned int* __restrict__ OFF,
                                                     unsigned short* __restrict__ bucket,
                                                     int* __restrict__ ovf_cnt,
                                                     int2* __restrict__ ovf, int nE) {
    __shared__ unsigned int cur[NW];  // 50 KB packed byte cursors
    const unsigned int* OFFb = OFF + (size_t)blockIdx.x * NW;
    for (int i = threadIdx.x; i < NW; i += 1024) cur[i] = OFFb[i];
    __syncthreads();
    int e0 = blockIdx.x * CHUNK;
    int e1 = min(e0 + CHUNK, nE);
    for (int e = e0 + (int)threadIdx.x; e < e1; e += 1024) {
        int s = src[e];
        int d = dst[e];
        int sh = 8 * (d & 3);
        unsigned int old = atomicAdd(&cur[d >> 2], 1u << sh);
        unsigned int q = (old >> sh) & 0xFFu;
        if (q < CAP) {
            bucket[(size_t)d * CAP + q] = (unsigned short)s;
        } else {
            int o = atomicAdd(ovf_cnt, 1);
            if (o < OVF_CAP) ovf[o] = make_int2(d, s);
        }
    }
}

// ---------------- fused: rs arrays + xs = bf16(x * rs_out), slice-major ----------------
__global__ void prescale_kernel(const float4* __restrict__ x, const int* __restrict__ cnt_s,
                                const int* __restrict__ cnt_d,
                                float* __restrict__ rs_out, float* __restrict__ rs_in,
                                ushort4* __restrict__ xs4, int nN) {
    int node = blockIdx.x * 8 + (threadIdx.x >> 5);
    int c = threadIdx.x & 31;
    if (node >= nN) return;
    float rs_o = 0.0f;
    if (c == 0) {
        rs_o = rsqrtf(fmaxf((float)cnt_s[node], 1.0f));
        rs_out[node] = rs_o;
        rs_in[node] = rsqrtf(fmaxf((float)cnt_d[node], 1.0f));
    }
    rs_o = __shfl(rs_o, threadIdx.x & 32);  // broadcast from node's lane 0 / 32
    float4 v = x[(size_t)node * 32 + c];
    ushort4 o;
    o.x = f2bf(v.x * rs_o);
    o.y = f2bf(v.y * rs_o);
    o.z = f2bf(v.z * rs_o);
    o.w = f2bf(v.w * rs_o);
    xs4[(size_t)(c >> 2) * SLICE_U4 + (size_t)node * 4 + (c & 3)] = o;
}

// ---------------- sliced gather over bucket CSR: slice = blockIdx%8, 4 lanes/node ----------------
__global__ void gather_kernel(const ushort4* __restrict__ xs4, const int* __restrict__ cnt_d,
                              const unsigned short* __restrict__ bucket,
                              float4* __restrict__ msg4, int nN) {
    int s = blockIdx.x & (NSLICE - 1);
    int g = blockIdx.x >> 3;
    int node = g * 64 + (threadIdx.x >> 2);
    int lane = threadIdx.x & 3;
    if (node >= nN) return;
    const ushort4* base = xs4 + (size_t)s * SLICE_U4;
    const unsigned short* bk = bucket + (size_t)node * CAP;
    int cnt = min(cnt_d[node], CAP);
    float4 a0 = make_float4(0.f, 0.f, 0.f, 0.f);
    float4 a1 = make_float4(0.f, 0.f, 0.f, 0.f);
    int e = 0;
    for (; e + 1 < cnt; e += 2) {
        int s0 = bk[e];
        int s1 = bk[e + 1];
        ushort4 v0 = base[(size_t)s0 * 4 + lane];
        ushort4 v1 = base[(size_t)s1 * 4 + lane];
        a0.x += bf2f(v0.x); a0.y += bf2f(v0.y); a0.z += bf2f(v0.z); a0.w += bf2f(v0.w);
        a1.x += bf2f(v1.x); a1.y += bf2f(v1.y); a1.z += bf2f(v1.z); a1.w += bf2f(v1.w);
    }
    if (e < cnt) {
        int s0 = bk[e];
        ushort4 v0 = base[(size_t)s0 * 4 + lane];
        a0.x += bf2f(v0.x); a0.y += bf2f(v0.y); a0.z += bf2f(v0.z); a0.w += bf2f(v0.w);
    }
    a0.x += a1.x; a0.y += a1.y; a0.z += a1.z; a0.w += a1.w;
    msg4[(size_t)s * SLICE_U4 + (size_t)node * 4 + lane] = a0;
}

// ---------------- overflow fixup (no-op when ovf_cnt==0; exact replay otherwise) ----------------
__global__ void ovf_kernel(const int2* __restrict__ ovf, const int* __restrict__ ovf_cnt,
                           const ushort4* __restrict__ xs4, float* __restrict__ msg) {
    int n = min(*ovf_cnt, OVF_CAP);
    int lane = threadIdx.x & 31;            // 32 lanes = 128 cols
    for (int i = (int)(threadIdx.x >> 5); i < n; i += 8) {
        int2 ds = ovf[i];
        int sl = lane >> 2, sub = lane & 3;
        ushort4 v = xs4[(size_t)sl * SLICE_U4 + (size_t)ds.y * 4 + sub];
        float* m = msg + ((size_t)sl * SLICE_U4 + (size_t)ds.x * 4 + sub) * 4;
        atomicAdd(m + 0, bf2f(v.x));
        atomicAdd(m + 1, bf2f(v.y));
        atomicAdd(m + 2, bf2f(v.z));
        atomicAdd(m + 3, bf2f(v.w));
    }
}

// ---------------- weight shuffle: WTs[k4*128 + col] = {W[4k4+j][col]} ----------------
__global__ void wshuf_kernel(const float* __restrict__ W1, float4* __restrict__ WTs1,
                             const float* __restrict__ W2, float4* __restrict__ WTs2) {
    int col = threadIdx.x;   // 0..127
    int k4 = blockIdx.x;     // 0..31
    const float* W = blockIdx.y ? W2 : W1;
    float4* WTs = blockIdx.y ? WTs2 : WTs1;
    WTs[k4 * D + col] = make_float4(W[(4 * k4 + 0) * D + col], W[(4 * k4 + 1) * D + col],
                                    W[(4 * k4 + 2) * D + col], W[(4 * k4 + 3) * D + col]);
}

// ---------------- dense layer: 64 nodes x 128 cols per block, 8x4 per thread ----------------
template <bool RELU_OUTSCALE, bool OUT_SLICED>
__global__ void gemm_kernel(const float4* __restrict__ msg4, const float* __restrict__ rs_in,
                            const float* __restrict__ rs_out, const float4* __restrict__ WTs,
                            const float* __restrict__ bias, void* __restrict__ outp, int nN) {
    __shared__ float4 sA[GN * 32];  // [node][k4], 32 KB
    int tid = threadIdx.x;          // 0..255
    int n0 = blockIdx.x * GN;
#pragma unroll
    for (int it = 0; it < 8; it++) {
        int idx = it * 256 + tid;
        int node = n0 + (idx >> 5);
        int c = idx & 31;           // k4 index
        sA[idx] = (node < nN)
            ? msg4[(size_t)(c >> 2) * SLICE_U4 + (size_t)node * 4 + (c & 3)]
            : make_float4(0.f, 0.f, 0.f, 0.f);
    }
    __syncthreads();
    int tx = tid & 31;   // cols tx, tx+32, tx+64, tx+96
    int ty = tid >> 5;   // nodes ty + 8*i
    float acc[8][4];
#pragma unroll
    for (int i = 0; i < 8; i++)
#pragma unroll
        for (int j = 0; j < 4; j++) acc[i][j] = 0.0f;

    for (int k4 = 0; k4 < 32; k4++) {
        float4 w0 = WTs[k4 * D + tx];
        float4 w1 = WTs[k4 * D + tx + 32];
        float4 w2 = WTs[k4 * D + tx + 64];
        float4 w3 = WTs[k4 * D + tx + 96];
#pragma unroll
        for (int i = 0; i < 8; i++) {
            float4 a = sA[(ty + 8 * i) * 32 + k4];
            acc[i][0] += a.x * w0.x + a.y * w0.y + a.z * w0.z + a.w * w0.w;
            acc[i][1] += a.x * w1.x + a.y * w1.y + a.z * w1.z + a.w * w1.w;
            acc[i][2] += a.x * w2.x + a.y * w2.y + a.z * w2.z + a.w * w2.w;
            acc[i][3] += a.x * w3.x + a.y * w3.y + a.z * w3.z + a.w * w3.w;
        }
    }
    float b0 = bias[tx], b1 = bias[tx + 32], b2 = bias[tx + 64], b3 = bias[tx + 96];
#pragma unroll
    for (int i = 0; i < 8; i++) {
        int node = n0 + ty + 8 * i;
        if (node >= nN) continue;
        float ri = rs_in[node];
        float v[4];
        v[0] = acc[i][0] * ri + b0;
        v[1] = acc[i][1] * ri + b1;
        v[2] = acc[i][2] * ri + b2;
        v[3] = acc[i][3] * ri + b3;
        if (RELU_OUTSCALE) {
            float ro = rs_out[node];
#pragma unroll
            for (int j = 0; j < 4; j++) v[j] = fmaxf(v[j], 0.0f) * ro;
        }
        if (OUT_SLICED) {
            bf16_t* o = (bf16_t*)outp;
#pragma unroll
            for (int j = 0; j < 4; j++) {
                int col = tx + 32 * j;
                o[(size_t)(col >> 4) * ((size_t)N_NODES * 16) + (size_t)node * 16 + (col & 15)] =
                    f2bf(v[j]);
            }
        } else {
            float* o = (float*)outp + (size_t)node * D;
            o[tx] = v[0]; o[tx + 32] = v[1]; o[tx + 64] = v[2]; o[tx + 96] = v[3];
        }
    }
}

static inline size_t align16(size_t x) { return (x + 15) & ~(size_t)15; }

extern "C" void kernel_launch(void* const* d_in, const int* in_sizes, int n_in,
                              void* d_out, int out_size, void* d_ws, size_t ws_size,
                              hipStream_t stream) {
    const float* x   = (const float*)d_in[0];
    const int*   src = (const int*)d_in[1];
    const int*   dst = (const int*)d_in[2];
    const float* W1  = (const float*)d_in[3];
    const float* b1  = (const float*)d_in[4];
    const float* W2  = (const float*)d_in[5];
    const float* b2  = (const float*)d_in[6];
    float* out = (float*)d_out;

    // workspace layout. xs aliases hs_buf (both sliced bf16).
    char* p = (char*)d_ws;
    float*          msg     = (float*)p;          p += align16((size_t)N_NODES * D * sizeof(float));
    int*            cnt_s   = (int*)p;            p += align16(N_NODES * sizeof(int));
    int*            cnt_d   = (int*)p;            p += align16(N_NODES * sizeof(int));
    int*            ovf_cnt = (int*)p;            p += align16(16 * sizeof(int));
    int2*           ovf     = (int2*)p;           p += align16((size_t)OVF_CAP * sizeof(int2));
    unsigned short* bucket  = (unsigned short*)p; p += align16((size_t)N_NODES * CAP * sizeof(unsigned short));
    float*          rs_out  = (float*)p;          p += align16(N_NODES * sizeof(float));
    float*          rs_in   = (float*)p;          p += align16(N_NODES * sizeof(float));
    float*          WTs1    = (float*)p;          p += align16((size_t)D * D * sizeof(float));
    float*          WTs2    = (float*)p;          p += align16((size_t)D * D * sizeof(float));
    bf16_t*         xs      = (bf16_t*)p;         // sliced bf16, aliased with hs (12.8 MB)
    bf16_t*         hs      = xs;

    // counting-sort scratch ALIASES msg (24 MB <= 25.6 MB); msg is fully
    // rewritten by gather_kernel after place_kernel completes.
    unsigned int* Hs  = (unsigned int*)msg;              // HB*NW*4 = 8.0 MB
    unsigned int* Hd  = Hs + (size_t)HB * NW;            // 8.0 MB
    unsigned int* OFF = Hd + (size_t)HB * NW;            // 8.0 MB

    // zero overflow counter only (cnt_s/cnt_d written densely by scan_kernel)
    hipMemsetAsync(ovf_cnt, 0, 16 * sizeof(int), stream);

    // weight shuffle (both layers, one tiny launch)
    wshuf_kernel<<<dim3(32, 2), D, 0, stream>>>(W1, (float4*)WTs1, W2, (float4*)WTs2);

    // counting-sort scatter: hist -> scan -> place (zero global atomics)
    hist_kernel<<<HB, 1024, 0, stream>>>(src, dst, Hs, Hd, N_EDGES);
    scan_kernel<<<dim3((NW + 255) / 256, 2), 256, 0, stream>>>(Hs, Hd, OFF, cnt_s, cnt_d);
    place_kernel<<<HB, 1024, 0, stream>>>(src, dst, OFF, bucket, ovf_cnt, ovf, N_EDGES);

    // rs arrays + xs = bf16(x * rs_out), slice-major
    prescale_kernel<<<(N_NODES + 7) / 8, 256, 0, stream>>>((const float4*)x, cnt_s, cnt_d,
                                                           rs_out, rs_in, (ushort4*)xs, N_NODES);

    // sliced gathers: 8 slices x 782 node-groups
    int ggrid = NSLICE * ((N_NODES + 63) / 64);

    // layer 1 aggregation: msg = sum xs[s]
    gather_kernel<<<ggrid, 256, 0, stream>>>((const ushort4*)xs, cnt_d, bucket,
                                             (float4*)msg, N_NODES);
    ovf_kernel<<<1, 256, 0, stream>>>(ovf, ovf_cnt, (const ushort4*)xs, msg);

    // layer 1 dense: hs = bf16( relu(rs_in * (msg @ W1) + b1) * rs_out ), slice-major
    gemm_kernel<true, true><<<(N_NODES + GN - 1) / GN, 256, 0, stream>>>(
        (const float4*)msg, rs_in, rs_out, (const float4*)WTs1, b1, hs, N_NODES);

    // layer 2 aggregation: msg = sum hs[s]
    gather_kernel<<<ggrid, 256, 0, stream>>>((const ushort4*)hs, cnt_d, bucket,
                                             (float4*)msg, N_NODES);
    ovf_kernel<<<1, 256, 0, stream>>>(ovf, ovf_cnt, (const ushort4*)hs, msg);

    // layer 2 dense: out = rs_in * (msg @ W2) + b2  (fp32 row-major)
    gemm_kernel<false, false><<<(N_NODES + GN - 1) / GN, 256, 0, stream>>>(
        (const float4*)msg, rs_in, nullptr, (const float4*)WTs2, b2, out, N_NODES);
}

// Round 4
// 284.616 us; speedup vs baseline: 1.2399x; 1.0543x over previous
//
#include <hip/hip_runtime.h>

#define N_NODES 50000
#define N_EDGES 800000
#define D 128
#define CAP 64      // bucket capacity per dst node (max in-degree ~45 for this dataset)
#define OVF_CAP 4096
#define GN 64       // nodes per GEMM block

#define HB 160                       // counting-sort blocks (chunks)
#define CHUNK ((N_EDGES + HB - 1) / HB)   // 5000 edges per chunk
#define NW (N_NODES / 4)             // packed byte-counter words = 12500

typedef unsigned short bf16_t;

__device__ inline float bf2f(bf16_t u) {
    union { unsigned int i; float f; } v;
    v.i = ((unsigned int)u) << 16;
    return v.f;
}
__device__ inline bf16_t f2bf(float f) {
    union { float f; unsigned int i; } v;
    v.f = f;
    unsigned int u = v.i;
    unsigned int r = (u + 0x7FFFu + ((u >> 16) & 1u)) >> 16;  // RNE
    return (bf16_t)r;
}
// bf16 pair packed in a u32 (little-endian: lo half = even col, hi half = odd col)
__device__ inline float u2f_lo(unsigned int u) {
    union { unsigned int i; float f; } x; x.i = u << 16; return x.f;
}
__device__ inline float u2f_hi(unsigned int u) {
    union { unsigned int i; float f; } x; x.i = u & 0xFFFF0000u; return x.f;
}

// =============== counting-sort scatter (zero global atomics) ===============
// Global device-scope atomics on gfx950 execute memory-side (~32 B fabric
// write each; measured rounds 0-2: WRITE_SIZE pinned ~51 MB for 1.6 M atomics
// regardless of partitioning). Per-block LDS histograms with packed byte
// counters (max degree ~45 < 255: 4 counters per u32, SWAR adds can't carry
// across fields), exclusive scan over blocks, then LDS-cursor placement.

// ---- K1: per-chunk src/dst histograms in LDS, flushed dense to global ----
__global__ __launch_bounds__(1024) void hist_kernel(const int* __restrict__ src,
                                                    const int* __restrict__ dst,
                                                    unsigned int* __restrict__ Hs,
                                                    unsigned int* __restrict__ Hd, int nE) {
    __shared__ unsigned int hs[NW];   // 50 KB
    __shared__ unsigned int hd[NW];   // 50 KB
    for (int i = threadIdx.x; i < NW; i += 1024) { hs[i] = 0u; hd[i] = 0u; }
    __syncthreads();
    int e0 = blockIdx.x * CHUNK;
    int e1 = min(e0 + CHUNK, nE);
    for (int e = e0 + (int)threadIdx.x; e < e1; e += 1024) {
        int s = src[e];
        int d = dst[e];
        atomicAdd(&hs[s >> 2], 1u << (8 * (s & 3)));
        atomicAdd(&hd[d >> 2], 1u << (8 * (d & 3)));
    }
    __syncthreads();
    unsigned int* Hsb = Hs + (size_t)blockIdx.x * NW;
    unsigned int* Hdb = Hd + (size_t)blockIdx.x * NW;
    for (int i = threadIdx.x; i < NW; i += 1024) { Hsb[i] = hs[i]; Hdb[i] = hd[i]; }
}

// ---- K2: exclusive scan across blocks (dst) + totals (src & dst) ----
__global__ void scan_kernel(const unsigned int* __restrict__ Hs,
                            const unsigned int* __restrict__ Hd,
                            unsigned int* __restrict__ OFF,
                            int* __restrict__ cnt_s, int* __restrict__ cnt_d) {
    int w = blockIdx.x * 256 + (int)threadIdx.x;
    if (w >= NW) return;
    if (blockIdx.y == 0) {
        unsigned int run = 0;
        for (int b = 0; b < HB; b++) {
            unsigned int v = Hd[(size_t)b * NW + w];
            OFF[(size_t)b * NW + w] = run;   // exclusive prefix, packed bytes (<=45 per field)
            run += v;                         // SWAR add: fields < 256, no cross-field carry
        }
        int4 c;
        c.x = (int)(run & 0xFFu); c.y = (int)((run >> 8) & 0xFFu);
        c.z = (int)((run >> 16) & 0xFFu); c.w = (int)(run >> 24);
        ((int4*)cnt_d)[w] = c;
    } else {
        unsigned int run = 0;
        for (int b = 0; b < HB; b++) run += Hs[(size_t)b * NW + w];
        int4 c;
        c.x = (int)(run & 0xFFu); c.y = (int)((run >> 8) & 0xFFu);
        c.z = (int)((run >> 16) & 0xFFu); c.w = (int)(run >> 24);
        ((int4*)cnt_s)[w] = c;
    }
}

// ---- K3: placement via packed LDS cursors (one LDS atomic per edge) ----
__global__ __launch_bounds__(1024) void place_kernel(const int* __restrict__ src,
                                                     const int* __restrict__ dst,
                                                     const unsigned int* __restrict__ OFF,
                                                     unsigned short* __restrict__ bucket,
                                                     int* __restrict__ ovf_cnt,
                                                     int2* __restrict__ ovf, int nE) {
    __shared__ unsigned int cur[NW];  // 50 KB packed byte cursors
    const unsigned int* OFFb = OFF + (size_t)blockIdx.x * NW;
    for (int i = threadIdx.x; i < NW; i += 1024) cur[i] = OFFb[i];
    __syncthreads();
    int e0 = blockIdx.x * CHUNK;
    int e1 = min(e0 + CHUNK, nE);
    for (int e = e0 + (int)threadIdx.x; e < e1; e += 1024) {
        int s = src[e];
        int d = dst[e];
        int sh = 8 * (d & 3);
        unsigned int old = atomicAdd(&cur[d >> 2], 1u << sh);
        unsigned int q = (old >> sh) & 0xFFu;
        if (q < CAP) {
            bucket[(size_t)d * CAP + q] = (unsigned short)s;
        } else {
            int o = atomicAdd(ovf_cnt, 1);
            if (o < OVF_CAP) ovf[o] = make_int2(d, s);
        }
    }
}

// ---------------- fused: rs arrays + xs = bf16(x * rs_out), ROW-MAJOR ----------------
__global__ void prescale_kernel(const float4* __restrict__ x, const int* __restrict__ cnt_s,
                                const int* __restrict__ cnt_d,
                                float* __restrict__ rs_out, float* __restrict__ rs_in,
                                ushort4* __restrict__ xs4, int nN) {
    int node = blockIdx.x * 8 + (threadIdx.x >> 5);
    int c = threadIdx.x & 31;
    if (node >= nN) return;
    float rs_o = 0.0f;
    if (c == 0) {
        rs_o = rsqrtf(fmaxf((float)cnt_s[node], 1.0f));
        rs_out[node] = rs_o;
        rs_in[node] = rsqrtf(fmaxf((float)cnt_d[node], 1.0f));
    }
    rs_o = __shfl(rs_o, threadIdx.x & 32);  // broadcast from node's lane 0 / 32
    float4 v = x[(size_t)node * 32 + c];
    ushort4 o;
    o.x = f2bf(v.x * rs_o);
    o.y = f2bf(v.y * rs_o);
    o.z = f2bf(v.z * rs_o);
    o.w = f2bf(v.w * rs_o);
    xs4[(size_t)node * 32 + c] = o;   // row-major: node row = 256 B
}

// ---------------- full-row gather over bucket CSR: 16 lanes/node, uint4 loads ----------------
// Per edge: one 256 B source row read by 16 lanes (4 cache lines), bucket row
// read ONCE per node (vs 8x in the sliced version). 4-way unrolled edge loop
// keeps 4 independent 16 B loads in flight per lane to cover L2/L3 latency.
__global__ void gather_kernel(const uint4* __restrict__ xs,   // bf16 row-major: 16 uint4/row
                              const int* __restrict__ cnt_d,
                              const unsigned short* __restrict__ bucket,
                              float4* __restrict__ msg4, int nN) {
    int node = blockIdx.x * 16 + ((int)threadIdx.x >> 4);
    int lane = threadIdx.x & 15;      // 16 B chunk index: cols [lane*8, lane*8+8)
    if (node >= nN) return;
    const unsigned short* bk = bucket + (size_t)node * CAP;
    int cnt = min(cnt_d[node], CAP);
    float a[8];
#pragma unroll
    for (int k = 0; k < 8; k++) a[k] = 0.f;
#define ACC8(v)                                              \
    a[0] += u2f_lo(v.x); a[1] += u2f_hi(v.x);                \
    a[2] += u2f_lo(v.y); a[3] += u2f_hi(v.y);                \
    a[4] += u2f_lo(v.z); a[5] += u2f_hi(v.z);                \
    a[6] += u2f_lo(v.w); a[7] += u2f_hi(v.w);
    int e = 0;
    for (; e + 3 < cnt; e += 4) {
        int s0 = bk[e], s1 = bk[e + 1], s2 = bk[e + 2], s3 = bk[e + 3];
        uint4 v0 = xs[(size_t)s0 * 16 + lane];
        uint4 v1 = xs[(size_t)s1 * 16 + lane];
        uint4 v2 = xs[(size_t)s2 * 16 + lane];
        uint4 v3 = xs[(size_t)s3 * 16 + lane];
        ACC8(v0) ACC8(v1) ACC8(v2) ACC8(v3)
    }
    for (; e < cnt; e++) {
        int s0 = bk[e];
        uint4 v0 = xs[(size_t)s0 * 16 + lane];
        ACC8(v0)
    }
#undef ACC8
    size_t o = (size_t)node * 32 + lane * 2;   // f32 row = 32 float4
    msg4[o]     = make_float4(a[0], a[1], a[2], a[3]);
    msg4[o + 1] = make_float4(a[4], a[5], a[6], a[7]);
}

// ---------------- overflow fixup (no-op when ovf_cnt==0; exact replay otherwise) ----------------
__global__ void ovf_kernel(const int2* __restrict__ ovf, const int* __restrict__ ovf_cnt,
                           const ushort4* __restrict__ xs4, float* __restrict__ msg) {
    int n = min(*ovf_cnt, OVF_CAP);
    int lane = threadIdx.x & 31;            // 32 lanes x 4 cols = 128
    for (int i = (int)(threadIdx.x >> 5); i < n; i += 8) {
        int2 ds = ovf[i];
        ushort4 v = xs4[(size_t)ds.y * 32 + lane];
        float* m = msg + (size_t)ds.x * D + lane * 4;
        atomicAdd(m + 0, bf2f(v.x));
        atomicAdd(m + 1, bf2f(v.y));
        atomicAdd(m + 2, bf2f(v.z));
        atomicAdd(m + 3, bf2f(v.w));
    }
}

// ---------------- weight shuffle: WTs[k4*128 + col] = {W[4k4+j][col]} ----------------
__global__ void wshuf_kernel(const float* __restrict__ W1, float4* __restrict__ WTs1,
                             const float* __restrict__ W2, float4* __restrict__ WTs2) {
    int col = threadIdx.x;   // 0..127
    int k4 = blockIdx.x;     // 0..31
    const float* W = blockIdx.y ? W2 : W1;
    float4* WTs = blockIdx.y ? WTs2 : WTs1;
    WTs[k4 * D + col] = make_float4(W[(4 * k4 + 0) * D + col], W[(4 * k4 + 1) * D + col],
                                    W[(4 * k4 + 2) * D + col], W[(4 * k4 + 3) * D + col]);
}

// ---------------- dense layer: 64 nodes x 128 cols per block, 8x4 per thread ----------------
template <bool RELU_OUTSCALE, bool OUT_BF16>
__global__ void gemm_kernel(const float4* __restrict__ msg4, const float* __restrict__ rs_in,
                            const float* __restrict__ rs_out, const float4* __restrict__ WTs,
                            const float* __restrict__ bias, void* __restrict__ outp, int nN) {
    __shared__ float4 sA[GN * 32];  // [node][k4], 32 KB
    int tid = threadIdx.x;          // 0..255
    int n0 = blockIdx.x * GN;
#pragma unroll
    for (int it = 0; it < 8; it++) {
        int idx = it * 256 + tid;
        int node = n0 + (idx >> 5);
        int c = idx & 31;           // k4 index
        sA[idx] = (node < nN)
            ? msg4[(size_t)node * 32 + c]   // row-major: node row = 32 float4
            : make_float4(0.f, 0.f, 0.f, 0.f);
    }
    __syncthreads();
    int tx = tid & 31;   // cols tx, tx+32, tx+64, tx+96
    int ty = tid >> 5;   // nodes ty + 8*i
    float acc[8][4];
#pragma unroll
    for (int i = 0; i < 8; i++)
#pragma unroll
        for (int j = 0; j < 4; j++) acc[i][j] = 0.0f;

    for (int k4 = 0; k4 < 32; k4++) {
        float4 w0 = WTs[k4 * D + tx];
        float4 w1 = WTs[k4 * D + tx + 32];
        float4 w2 = WTs[k4 * D + tx + 64];
        float4 w3 = WTs[k4 * D + tx + 96];
#pragma unroll
        for (int i = 0; i < 8; i++) {
            float4 a = sA[(ty + 8 * i) * 32 + k4];
            acc[i][0] += a.x * w0.x + a.y * w0.y + a.z * w0.z + a.w * w0.w;
            acc[i][1] += a.x * w1.x + a.y * w1.y + a.z * w1.z + a.w * w1.w;
            acc[i][2] += a.x * w2.x + a.y * w2.y + a.z * w2.z + a.w * w2.w;
            acc[i][3] += a.x * w3.x + a.y * w3.y + a.z * w3.z + a.w * w3.w;
        }
    }
    float b0 = bias[tx], b1 = bias[tx + 32], b2 = bias[tx + 64], b3 = bias[tx + 96];
#pragma unroll
    for (int i = 0; i < 8; i++) {
        int node = n0 + ty + 8 * i;
        if (node >= nN) continue;
        float ri = rs_in[node];
        float v[4];
        v[0] = acc[i][0] * ri + b0;
        v[1] = acc[i][1] * ri + b1;
        v[2] = acc[i][2] * ri + b2;
        v[3] = acc[i][3] * ri + b3;
        if (RELU_OUTSCALE) {
            float ro = rs_out[node];
#pragma unroll
            for (int j = 0; j < 4; j++) v[j] = fmaxf(v[j], 0.0f) * ro;
        }
        if (OUT_BF16) {
            bf16_t* o = (bf16_t*)outp;
#pragma unroll
            for (int j = 0; j < 4; j++) {
                int col = tx + 32 * j;
                o[(size_t)node * D + col] = f2bf(v[j]);  // row-major bf16
            }
        } else {
            float* o = (float*)outp + (size_t)node * D;
            o[tx] = v[0]; o[tx + 32] = v[1]; o[tx + 64] = v[2]; o[tx + 96] = v[3];
        }
    }
}

static inline size_t align16(size_t x) { return (x + 15) & ~(size_t)15; }

extern "C" void kernel_launch(void* const* d_in, const int* in_sizes, int n_in,
                              void* d_out, int out_size, void* d_ws, size_t ws_size,
                              hipStream_t stream) {
    const float* x   = (const float*)d_in[0];
    const int*   src = (const int*)d_in[1];
    const int*   dst = (const int*)d_in[2];
    const float* W1  = (const float*)d_in[3];
    const float* b1  = (const float*)d_in[4];
    const float* W2  = (const float*)d_in[5];
    const float* b2  = (const float*)d_in[6];
    float* out = (float*)d_out;

    // workspace layout. xs aliases hs (both row-major bf16).
    char* p = (char*)d_ws;
    float*          msg     = (float*)p;          p += align16((size_t)N_NODES * D * sizeof(float));
    int*            cnt_s   = (int*)p;            p += align16(N_NODES * sizeof(int));
    int*            cnt_d   = (int*)p;            p += align16(N_NODES * sizeof(int));
    int*            ovf_cnt = (int*)p;            p += align16(16 * sizeof(int));
    int2*           ovf     = (int2*)p;           p += align16((size_t)OVF_CAP * sizeof(int2));
    unsigned short* bucket  = (unsigned short*)p; p += align16((size_t)N_NODES * CAP * sizeof(unsigned short));
    float*          rs_out  = (float*)p;          p += align16(N_NODES * sizeof(float));
    float*          rs_in   = (float*)p;          p += align16(N_NODES * sizeof(float));
    float*          WTs1    = (float*)p;          p += align16((size_t)D * D * sizeof(float));
    float*          WTs2    = (float*)p;          p += align16((size_t)D * D * sizeof(float));
    bf16_t*         xs      = (bf16_t*)p;         // row-major bf16, aliased with hs (12.8 MB)
    bf16_t*         hs      = xs;

    // counting-sort scratch ALIASES msg (24 MB <= 25.6 MB); msg is fully
    // rewritten by gather_kernel after place_kernel completes.
    unsigned int* Hs  = (unsigned int*)msg;              // HB*NW*4 = 8.0 MB
    unsigned int* Hd  = Hs + (size_t)HB * NW;            // 8.0 MB
    unsigned int* OFF = Hd + (size_t)HB * NW;            // 8.0 MB

    // zero overflow counter only (cnt_s/cnt_d written densely by scan_kernel)
    hipMemsetAsync(ovf_cnt, 0, 16 * sizeof(int), stream);

    // weight shuffle (both layers, one tiny launch)
    wshuf_kernel<<<dim3(32, 2), D, 0, stream>>>(W1, (float4*)WTs1, W2, (float4*)WTs2);

    // counting-sort scatter: hist -> scan -> place (zero global atomics)
    hist_kernel<<<HB, 1024, 0, stream>>>(src, dst, Hs, Hd, N_EDGES);
    scan_kernel<<<dim3((NW + 255) / 256, 2), 256, 0, stream>>>(Hs, Hd, OFF, cnt_s, cnt_d);
    place_kernel<<<HB, 1024, 0, stream>>>(src, dst, OFF, bucket, ovf_cnt, ovf, N_EDGES);

    // rs arrays + xs = bf16(x * rs_out), row-major
    prescale_kernel<<<(N_NODES + 7) / 8, 256, 0, stream>>>((const float4*)x, cnt_s, cnt_d,
                                                           rs_out, rs_in, (ushort4*)xs, N_NODES);

    int ggrid = (N_NODES + 15) / 16;   // 16 nodes per block

    // layer 1 aggregation: msg = sum xs[s]
    gather_kernel<<<ggrid, 256, 0, stream>>>((const uint4*)xs, cnt_d, bucket,
                                             (float4*)msg, N_NODES);
    ovf_kernel<<<1, 256, 0, stream>>>(ovf, ovf_cnt, (const ushort4*)xs, msg);

    // layer 1 dense: hs = bf16( relu(rs_in * (msg @ W1) + b1) * rs_out ), row-major
    gemm_kernel<true, true><<<(N_NODES + GN - 1) / GN, 256, 0, stream>>>(
        (const float4*)msg, rs_in, rs_out, (const float4*)WTs1, b1, hs, N_NODES);

    // layer 2 aggregation: msg = sum hs[s]
    gather_kernel<<<ggrid, 256, 0, stream>>>((const uint4*)hs, cnt_d, bucket,
                                             (float4*)msg, N_NODES);
    ovf_kernel<<<1, 256, 0, stream>>>(ovf, ovf_cnt, (const ushort4*)hs, msg);

    // layer 2 dense: out = rs_in * (msg @ W2) + b2  (fp32 row-major)
    gemm_kernel<false, false><<<(N_NODES + GN - 1) / GN, 256, 0, stream>>>(
        (const float4*)msg, rs_in, nullptr, (const float4*)WTs2, b2, out, N_NODES);
}

// Round 5
// 243.003 us; speedup vs baseline: 1.4522x; 1.1712x over previous
//
#include <hip/hip_runtime.h>

#define N_NODES 50000
#define N_EDGES 800000
#define D 128
#define CAP 64      // bucket capacity per dst node (max in-degree ~45 for this dataset)
#define OVF_CAP 4096

#define HB 160                       // counting-sort blocks (chunks)
#define CHUNK ((N_EDGES + HB - 1) / HB)   // 5000 edges per chunk
#define NW (N_NODES / 4)             // packed byte-counter words = 12500

typedef unsigned short bf16_t;
typedef __attribute__((ext_vector_type(8))) short short8v;   // 8 bf16 = 4 VGPR (MFMA A/B frag)
typedef __attribute__((ext_vector_type(4))) float f32x4;     // MFMA C/D frag

__device__ inline float bf2f(bf16_t u) {
    union { unsigned int i; float f; } v;
    v.i = ((unsigned int)u) << 16;
    return v.f;
}
__device__ inline bf16_t f2bf(float f) {
    union { float f; unsigned int i; } v;
    v.f = f;
    unsigned int u = v.i;
    unsigned int r = (u + 0x7FFFu + ((u >> 16) & 1u)) >> 16;  // RNE
    return (bf16_t)r;
}
// bf16 pair packed in a u32 (little-endian: lo half = even col, hi half = odd col)
__device__ inline float u2f_lo(unsigned int u) {
    union { unsigned int i; float f; } x; x.i = u << 16; return x.f;
}
__device__ inline float u2f_hi(unsigned int u) {
    union { unsigned int i; float f; } x; x.i = u & 0xFFFF0000u; return x.f;
}

// =============== counting-sort scatter (zero global atomics) ===============
// Global device-scope atomics on gfx950 execute memory-side (~32 B fabric
// write each; measured rounds 0-2: WRITE_SIZE pinned ~51 MB for 1.6 M atomics
// regardless of partitioning). Per-block LDS histograms with packed byte
// counters (max degree ~45 < 255: 4 counters per u32, SWAR adds can't carry
// across fields), exclusive scan over blocks, then LDS-cursor placement.

// ---- K1: per-chunk src/dst histograms in LDS, flushed dense to global ----
__global__ __launch_bounds__(1024) void hist_kernel(const int* __restrict__ src,
                                                    const int* __restrict__ dst,
                                                    unsigned int* __restrict__ Hs,
                                                    unsigned int* __restrict__ Hd, int nE) {
    __shared__ unsigned int hs[NW];   // 50 KB
    __shared__ unsigned int hd[NW];   // 50 KB
    for (int i = threadIdx.x; i < NW; i += 1024) { hs[i] = 0u; hd[i] = 0u; }
    __syncthreads();
    int e0 = blockIdx.x * CHUNK;
    int e1 = min(e0 + CHUNK, nE);
    for (int e = e0 + (int)threadIdx.x; e < e1; e += 1024) {
        int s = src[e];
        int d = dst[e];
        atomicAdd(&hs[s >> 2], 1u << (8 * (s & 3)));
        atomicAdd(&hd[d >> 2], 1u << (8 * (d & 3)));
    }
    __syncthreads();
    unsigned int* Hsb = Hs + (size_t)blockIdx.x * NW;
    unsigned int* Hdb = Hd + (size_t)blockIdx.x * NW;
    for (int i = threadIdx.x; i < NW; i += 1024) { Hsb[i] = hs[i]; Hdb[i] = hd[i]; }
}

// ---- K2: exclusive scan across blocks (dst) + totals (src & dst) ----
__global__ void scan_kernel(const unsigned int* __restrict__ Hs,
                            const unsigned int* __restrict__ Hd,
                            unsigned int* __restrict__ OFF,
                            int* __restrict__ cnt_s, int* __restrict__ cnt_d) {
    int w = blockIdx.x * 256 + (int)threadIdx.x;
    if (w >= NW) return;
    if (blockIdx.y == 0) {
        unsigned int run = 0;
        for (int b = 0; b < HB; b++) {
            unsigned int v = Hd[(size_t)b * NW + w];
            OFF[(size_t)b * NW + w] = run;   // exclusive prefix, packed bytes (<=45 per field)
            run += v;                         // SWAR add: fields < 256, no cross-field carry
        }
        int4 c;
        c.x = (int)(run & 0xFFu); c.y = (int)((run >> 8) & 0xFFu);
        c.z = (int)((run >> 16) & 0xFFu); c.w = (int)(run >> 24);
        ((int4*)cnt_d)[w] = c;
    } else {
        unsigned int run = 0;
        for (int b = 0; b < HB; b++) run += Hs[(size_t)b * NW + w];
        int4 c;
        c.x = (int)(run & 0xFFu); c.y = (int)((run >> 8) & 0xFFu);
        c.z = (int)((run >> 16) & 0xFFu); c.w = (int)(run >> 24);
        ((int4*)cnt_s)[w] = c;
    }
}

// ---- K3: placement via packed LDS cursors (one LDS atomic per edge) ----
__global__ __launch_bounds__(1024) void place_kernel(const int* __restrict__ src,
                                                     const int* __restrict__ dst,
                                                     const unsigned int* __restrict__ OFF,
                                                     unsigned short* __restrict__ bucket,
                                                     int* __restrict__ ovf_cnt,
                                                     int2* __restrict__ ovf, int nE) {
    __shared__ unsigned int cur[NW];  // 50 KB packed byte cursors
    const unsigned int* OFFb = OFF + (size_t)blockIdx.x * NW;
    for (int i = threadIdx.x; i < NW; i += 1024) cur[i] = OFFb[i];
    __syncthreads();
    int e0 = blockIdx.x * CHUNK;
    int e1 = min(e0 + CHUNK, nE);
    for (int e = e0 + (int)threadIdx.x; e < e1; e += 1024) {
        int s = src[e];
        int d = dst[e];
        int sh = 8 * (d & 3);
        unsigned int old = atomicAdd(&cur[d >> 2], 1u << sh);
        unsigned int q = (old >> sh) & 0xFFu;
        if (q < CAP) {
            bucket[(size_t)d * CAP + q] = (unsigned short)s;
        } else {
            int o = atomicAdd(ovf_cnt, 1);
            if (o < OVF_CAP) ovf[o] = make_int2(d, s);
        }
    }
}

// ---------------- fused: rs arrays + xs = bf16(x * rs_out), ROW-MAJOR ----------------
__global__ void prescale_kernel(const float4* __restrict__ x, const int* __restrict__ cnt_s,
                                const int* __restrict__ cnt_d,
                                float* __restrict__ rs_out, float* __restrict__ rs_in,
                                ushort4* __restrict__ xs4, int nN) {
    int node = blockIdx.x * 8 + (threadIdx.x >> 5);
    int c = threadIdx.x & 31;
    if (node >= nN) return;
    float rs_o = 0.0f;
    if (c == 0) {
        rs_o = rsqrtf(fmaxf((float)cnt_s[node], 1.0f));
        rs_out[node] = rs_o;
        rs_in[node] = rsqrtf(fmaxf((float)cnt_d[node], 1.0f));
    }
    rs_o = __shfl(rs_o, threadIdx.x & 32);  // broadcast from node's lane 0 / 32
    float4 v = x[(size_t)node * 32 + c];
    ushort4 o;
    o.x = f2bf(v.x * rs_o);
    o.y = f2bf(v.y * rs_o);
    o.z = f2bf(v.z * rs_o);
    o.w = f2bf(v.w * rs_o);
    xs4[(size_t)node * 32 + c] = o;   // row-major: node row = 256 B
}

// ---------------- full-row gather over bucket CSR: 16 lanes/node, uint4 loads ----------------
__global__ void gather_kernel(const uint4* __restrict__ xs,   // bf16 row-major: 16 uint4/row
                              const int* __restrict__ cnt_d,
                              const unsigned short* __restrict__ bucket,
                              float4* __restrict__ msg4, int nN) {
    int node = blockIdx.x * 16 + ((int)threadIdx.x >> 4);
    int lane = threadIdx.x & 15;      // 16 B chunk index: cols [lane*8, lane*8+8)
    if (node >= nN) return;
    const unsigned short* bk = bucket + (size_t)node * CAP;
    int cnt = min(cnt_d[node], CAP);
    float a[8];
#pragma unroll
    for (int k = 0; k < 8; k++) a[k] = 0.f;
#define ACC8(v)                                              \
    a[0] += u2f_lo(v.x); a[1] += u2f_hi(v.x);                \
    a[2] += u2f_lo(v.y); a[3] += u2f_hi(v.y);                \
    a[4] += u2f_lo(v.z); a[5] += u2f_hi(v.z);                \
    a[6] += u2f_lo(v.w); a[7] += u2f_hi(v.w);
    int e = 0;
    for (; e + 3 < cnt; e += 4) {
        int s0 = bk[e], s1 = bk[e + 1], s2 = bk[e + 2], s3 = bk[e + 3];
        uint4 v0 = xs[(size_t)s0 * 16 + lane];
        uint4 v1 = xs[(size_t)s1 * 16 + lane];
        uint4 v2 = xs[(size_t)s2 * 16 + lane];
        uint4 v3 = xs[(size_t)s3 * 16 + lane];
        ACC8(v0) ACC8(v1) ACC8(v2) ACC8(v3)
    }
    for (; e < cnt; e++) {
        int s0 = bk[e];
        uint4 v0 = xs[(size_t)s0 * 16 + lane];
        ACC8(v0)
    }
#undef ACC8
    size_t o = (size_t)node * 32 + lane * 2;   // f32 row = 32 float4
    msg4[o]     = make_float4(a[0], a[1], a[2], a[3]);
    msg4[o + 1] = make_float4(a[4], a[5], a[6], a[7]);
}

// ---------------- overflow fixup (no-op when ovf_cnt==0; exact replay otherwise) ----------------
__global__ void ovf_kernel(const int2* __restrict__ ovf, const int* __restrict__ ovf_cnt,
                           const ushort4* __restrict__ xs4, float* __restrict__ msg) {
    int n = min(*ovf_cnt, OVF_CAP);
    int lane = threadIdx.x & 31;            // 32 lanes x 4 cols = 128
    for (int i = (int)(threadIdx.x >> 5); i < n; i += 8) {
        int2 ds = ovf[i];
        ushort4 v = xs4[(size_t)ds.y * 32 + lane];
        float* m = msg + (size_t)ds.x * D + lane * 4;
        atomicAdd(m + 0, bf2f(v.x));
        atomicAdd(m + 1, bf2f(v.y));
        atomicAdd(m + 2, bf2f(v.z));
        atomicAdd(m + 3, bf2f(v.w));
    }
}

// ---------------- W hi/lo split into MFMA B-fragment layout ----------------
// Wf layout: [hi | lo], each 2048 frags of short8. frag index flat = (ks*8+c)*64+lane;
// element j: B[k = ks*32 + (lane>>4)*8 + j][n = c*16 + (lane&15)]  (B = W, K x N row-major).
__global__ void wsplit_kernel(const float* __restrict__ W1, bf16_t* __restrict__ Wf1,
                              const float* __restrict__ W2, bf16_t* __restrict__ Wf2) {
    const float* W = blockIdx.y ? W2 : W1;
    bf16_t* Wf = blockIdx.y ? Wf2 : Wf1;
    int flat = blockIdx.x * 256 + (int)threadIdx.x;   // 0..2047 (grid.x = 8)
    int lane = flat & 63;
    int c = (flat >> 6) & 7;
    int ks = flat >> 9;
    int n = c * 16 + (lane & 15);
    int kb = ks * 32 + (lane >> 4) * 8;
#pragma unroll
    for (int j = 0; j < 8; j++) {
        float w = W[(size_t)(kb + j) * D + n];
        bf16_t hi = f2bf(w);
        bf16_t lo = f2bf(w - bf2f(hi));
        Wf[(size_t)flat * 8 + j] = hi;
        Wf[(size_t)(2048 + flat) * 8 + j] = lo;
    }
}

// ---------------- MFMA dense layer: split-bf16 (3-term Markidis) ----------------
// Per wave: 16 nodes x 128 cols, K=128. a = ah + al (bf16 split, in-register);
// w = wh + wl (pre-split). a*w ~= ah*wh + al*wh + ah*wl; dropped al*wl ~ 2^-18 rel.
// Fragment maps (guide §3, HW-verified): A: lane holds A[lane&15][(lane>>4)*8+j];
// B: lane holds B[(lane>>4)*8+j][lane&15]; C/D: col=lane&15, row=(lane>>4)*4+reg.
template <bool RELU_OUTSCALE, bool OUT_BF16>
__global__ __launch_bounds__(256) void gemm_mfma_kernel(
    const float* __restrict__ msg, const float* __restrict__ rs_in,
    const float* __restrict__ rs_out, const bf16_t* __restrict__ Wf,
    const float* __restrict__ bias, void* __restrict__ outp, int nN) {
    int lane = (int)threadIdx.x & 63;
    int wave = (int)threadIdx.x >> 6;
    int n0 = blockIdx.x * 64 + wave * 16;   // wave's 16-node tile
    int ar = lane & 15;                     // A row within tile
    int kg = lane >> 4;                     // k-subchunk of 8

    // ---- load A rows from global, split to bf16 hi/lo in-register ----
    short8v ahi[4], alo[4];
    {
        const float* ap = msg + (size_t)(n0 + ar) * D + kg * 8;
        bool valid = (n0 + ar) < nN;
#pragma unroll
        for (int ks = 0; ks < 4; ks++) {
            float av[8];
            if (valid) {
                float4 p0 = *(const float4*)(ap + ks * 32);
                float4 p1 = *(const float4*)(ap + ks * 32 + 4);
                av[0] = p0.x; av[1] = p0.y; av[2] = p0.z; av[3] = p0.w;
                av[4] = p1.x; av[5] = p1.y; av[6] = p1.z; av[7] = p1.w;
            } else {
#pragma unroll
                for (int j = 0; j < 8; j++) av[j] = 0.f;
            }
#pragma unroll
            for (int j = 0; j < 8; j++) {
                bf16_t h = f2bf(av[j]);
                bf16_t l = f2bf(av[j] - bf2f(h));
                ahi[ks][j] = (short)h;
                alo[ks][j] = (short)l;
            }
        }
    }

    f32x4 acc[8];
#pragma unroll
    for (int c = 0; c < 8; c++) acc[c] = (f32x4){0.f, 0.f, 0.f, 0.f};

    const short8v* Bh = (const short8v*)Wf;        // 2048 hi frags
    const short8v* Bl = Bh + 2048;                 // 2048 lo frags
#pragma unroll
    for (int ks = 0; ks < 4; ks++) {
#pragma unroll
        for (int c = 0; c < 8; c++) {
            int off = (ks * 8 + c) * 64 + lane;
            short8v wh = Bh[off];
            short8v wl = Bl[off];
            acc[c] = __builtin_amdgcn_mfma_f32_16x16x32_bf16(ahi[ks], wh, acc[c], 0, 0, 0);
            acc[c] = __builtin_amdgcn_mfma_f32_16x16x32_bf16(alo[ks], wh, acc[c], 0, 0, 0);
            acc[c] = __builtin_amdgcn_mfma_f32_16x16x32_bf16(ahi[ks], wl, acc[c], 0, 0, 0);
        }
    }

    // ---- epilogue: col = c*16 + (lane&15), node = n0 + kg*4 + r ----
    int ocol = lane & 15;
#pragma unroll
    for (int r = 0; r < 4; r++) {
        int node = n0 + kg * 4 + r;
        if (node >= nN) continue;
        float ri = rs_in[node];
        float ro = RELU_OUTSCALE ? rs_out[node] : 1.0f;
#pragma unroll
        for (int c = 0; c < 8; c++) {
            float v = acc[c][r] * ri + bias[c * 16 + ocol];
            if (RELU_OUTSCALE) v = fmaxf(v, 0.0f) * ro;
            if (OUT_BF16) {
                ((bf16_t*)outp)[(size_t)node * D + c * 16 + ocol] = f2bf(v);
            } else {
                ((float*)outp)[(size_t)node * D + c * 16 + ocol] = v;
            }
        }
    }
}

static inline size_t align16(size_t x) { return (x + 15) & ~(size_t)15; }

extern "C" void kernel_launch(void* const* d_in, const int* in_sizes, int n_in,
                              void* d_out, int out_size, void* d_ws, size_t ws_size,
                              hipStream_t stream) {
    const float* x   = (const float*)d_in[0];
    const int*   src = (const int*)d_in[1];
    const int*   dst = (const int*)d_in[2];
    const float* W1  = (const float*)d_in[3];
    const float* b1  = (const float*)d_in[4];
    const float* W2  = (const float*)d_in[5];
    const float* b2  = (const float*)d_in[6];
    float* out = (float*)d_out;

    // workspace layout. xs aliases hs (both row-major bf16).
    char* p = (char*)d_ws;
    float*          msg     = (float*)p;          p += align16((size_t)N_NODES * D * sizeof(float));
    int*            cnt_s   = (int*)p;            p += align16(N_NODES * sizeof(int));
    int*            cnt_d   = (int*)p;            p += align16(N_NODES * sizeof(int));
    int*            ovf_cnt = (int*)p;            p += align16(16 * sizeof(int));
    int2*           ovf     = (int2*)p;           p += align16((size_t)OVF_CAP * sizeof(int2));
    unsigned short* bucket  = (unsigned short*)p; p += align16((size_t)N_NODES * CAP * sizeof(unsigned short));
    float*          rs_out  = (float*)p;          p += align16(N_NODES * sizeof(float));
    float*          rs_in   = (float*)p;          p += align16(N_NODES * sizeof(float));
    bf16_t*         Wf1     = (bf16_t*)p;         p += align16((size_t)2 * 2048 * 8 * sizeof(bf16_t));
    bf16_t*         Wf2     = (bf16_t*)p;         p += align16((size_t)2 * 2048 * 8 * sizeof(bf16_t));
    bf16_t*         xs      = (bf16_t*)p;         // row-major bf16, aliased with hs (12.8 MB)
    bf16_t*         hs      = xs;

    // counting-sort scratch ALIASES msg (24 MB <= 25.6 MB); msg is fully
    // rewritten by gather_kernel after place_kernel completes.
    unsigned int* Hs  = (unsigned int*)msg;              // HB*NW*4 = 8.0 MB
    unsigned int* Hd  = Hs + (size_t)HB * NW;            // 8.0 MB
    unsigned int* OFF = Hd + (size_t)HB * NW;            // 8.0 MB

    // zero overflow counter only (cnt_s/cnt_d written densely by scan_kernel)
    hipMemsetAsync(ovf_cnt, 0, 16 * sizeof(int), stream);

    // weight hi/lo split into MFMA fragment layout (both layers, one tiny launch)
    wsplit_kernel<<<dim3(8, 2), 256, 0, stream>>>(W1, Wf1, W2, Wf2);

    // counting-sort scatter: hist -> scan -> place (zero global atomics)
    hist_kernel<<<HB, 1024, 0, stream>>>(src, dst, Hs, Hd, N_EDGES);
    scan_kernel<<<dim3((NW + 255) / 256, 2), 256, 0, stream>>>(Hs, Hd, OFF, cnt_s, cnt_d);
    place_kernel<<<HB, 1024, 0, stream>>>(src, dst, OFF, bucket, ovf_cnt, ovf, N_EDGES);

    // rs arrays + xs = bf16(x * rs_out), row-major
    prescale_kernel<<<(N_NODES + 7) / 8, 256, 0, stream>>>((const float4*)x, cnt_s, cnt_d,
                                                           rs_out, rs_in, (ushort4*)xs, N_NODES);

    int ggrid = (N_NODES + 15) / 16;   // 16 nodes per block
    int mgrid = (N_NODES + 63) / 64;   // 64 nodes per MFMA-GEMM block

    // layer 1 aggregation: msg = sum xs[s]
    gather_kernel<<<ggrid, 256, 0, stream>>>((const uint4*)xs, cnt_d, bucket,
                                             (float4*)msg, N_NODES);
    ovf_kernel<<<1, 256, 0, stream>>>(ovf, ovf_cnt, (const ushort4*)xs, msg);

    // layer 1 dense: hs = bf16( relu(rs_in * (msg @ W1) + b1) * rs_out ), row-major
    gemm_mfma_kernel<true, true><<<mgrid, 256, 0, stream>>>(
        msg, rs_in, rs_out, Wf1, b1, hs, N_NODES);

    // layer 2 aggregation: msg = sum hs[s]
    gather_kernel<<<ggrid, 256, 0, stream>>>((const uint4*)hs, cnt_d, bucket,
                                             (float4*)msg, N_NODES);
    ovf_kernel<<<1, 256, 0, stream>>>(ovf, ovf_cnt, (const ushort4*)hs, msg);

    // layer 2 dense: out = rs_in * (msg @ W2) + b2  (fp32 row-major)
    gemm_mfma_kernel<false, false><<<mgrid, 256, 0, stream>>>(
        msg, rs_in, nullptr, Wf2, b2, out, N_NODES);
}